// Round 9
// baseline (1410.191 us; speedup 1.0000x reference)
//
#include <hip/hip_runtime.h>
#include <hip/hip_bf16.h>
#include <math.h>

#define NNODES 50000
#define NEDGES 500000
#define NLAYERS 8
#define NSCANB 196  // ceil(NNODES/256)
#define CSRMAX (NEDGES + 7 * NNODES)  // padded-to-8 worst case
#define NPST 782    // 391 m-tiles x 2 n-halves = gemm blocks = stat slots

typedef __attribute__((ext_vector_type(8))) short bhalf8;
typedef __attribute__((ext_vector_type(4))) float f32x4;

// K-dim permutation: packed pos p <-> natural dim d = 16*(p&7) + (p>>3).
static __device__ __forceinline__ int invp(int p) { return 16 * (p & 7) + (p >> 3); }

static __device__ __forceinline__ unsigned short f2b(float v) {
    unsigned u = __builtin_bit_cast(unsigned, v);
    u += 0x7fffu + ((u >> 16) & 1u);
    return (unsigned short)(u >> 16);
}
static __device__ __forceinline__ float b2f(unsigned short w) {
    return __builtin_bit_cast(float, (unsigned)w << 16);
}
static __device__ __forceinline__ float b2f_lo(unsigned w) {
    return __builtin_bit_cast(float, w << 16);
}
static __device__ __forceinline__ float b2f_hi(unsigned w) {
    return __builtin_bit_cast(float, w & 0xffff0000u);
}
static __device__ __forceinline__ float ub(unsigned a, int k) {
    return (float)((a >> (8 * k)) & 0xffu);  // folds to v_cvt_f32_ubyteN
}

// ---------------- graph preprocessing ----------------

__global__ void k_count(const int* __restrict__ col, int* __restrict__ counts) {
    int e = blockIdx.x * 256 + threadIdx.x;
    if (e < NEDGES) atomicAdd(&counts[col[e]], 1);
}

__global__ __launch_bounds__(256) void k_dinv_bsum(const int* __restrict__ counts,
                                                   float* __restrict__ dinv,
                                                   int* __restrict__ part) {
    __shared__ int ls[256];
    int t = threadIdx.x, i = blockIdx.x * 256 + t;
    int cnt = (i < NNODES) ? counts[i] : 0;
    if (i < NNODES) dinv[i] = rsqrtf((float)(cnt + 1));
    ls[t] = (i < NNODES) ? ((cnt + 7) & ~7) : 0;
    __syncthreads();
    for (int o = 128; o > 0; o >>= 1) {
        if (t < o) ls[t] += ls[t + o];
        __syncthreads();
    }
    if (t == 0) part[blockIdx.x] = ls[0];
}

__global__ __launch_bounds__(256) void k_pscan(int* __restrict__ part) {
    __shared__ int ls[256];
    int t = threadIdx.x;
    int v = (t < NSCANB) ? part[t] : 0;
    ls[t] = v;
    __syncthreads();
    for (int o = 1; o < 256; o <<= 1) {
        int x = (t >= o) ? ls[t - o] : 0;
        __syncthreads();
        ls[t] += x;
        __syncthreads();
    }
    if (t < NSCANB) part[t] = ls[t] - v;
}

__global__ __launch_bounds__(256) void k_offs(const int* __restrict__ counts,
                                              const int* __restrict__ part,
                                              int* __restrict__ offs) {
    __shared__ int ls[256];
    int t = threadIdx.x, i = blockIdx.x * 256 + t;
    int v = (i < NNODES) ? ((counts[i] + 7) & ~7) : 0;
    ls[t] = v;
    __syncthreads();
    for (int o = 1; o < 256; o <<= 1) {
        int x = (t >= o) ? ls[t - o] : 0;
        __syncthreads();
        ls[t] += x;
        __syncthreads();
    }
    int excl = part[blockIdx.x] + ls[t] - v;
    if (i < NNODES) offs[i] = excl;
    if (i == NNODES - 1) offs[NNODES] = excl + v;
}

// csr pre-memset to 0 -> pad entries are {row 0, w 0.0f}
__global__ void k_scatter(const int* __restrict__ row, const int* __restrict__ col,
                          const int* __restrict__ offs, int* __restrict__ cursor,
                          const float* __restrict__ dinv, int2* __restrict__ csr) {
    int e = blockIdx.x * 256 + threadIdx.x;
    if (e < NEDGES) {
        int c = col[e], r = row[e];
        int pos = offs[c] + atomicAdd(&cursor[c], 1);
        float w = dinv[r] * dinv[c];
        csr[pos] = make_int2(r, __builtin_bit_cast(int, w));
    }
}

// ---------------- folded + packed layer weights (K-permuted) ----------------
__global__ void k_wcp2(const float* __restrict__ w1, const float* __restrict__ w2,
                       unsigned short* __restrict__ Wp) {
    int idx = blockIdx.x * 256 + threadIdx.x;
    if (idx >= NLAYERS * 32768) return;
    int i = idx >> 15;
    int rem = idx & 32767;
    int s = rem >> 12;
    int t = (rem >> 9) & 7;
    int lane = (rem >> 3) & 63;
    int j = rem & 7;
    int kf = s * 32 + (lane >> 4) * 8 + j;
    int n = t * 16 + (lane & 15);
    float beta = logf(1.0f / (float)(i + 1) + 1.0f);
    float v;
    if (kf < 128) {
        int k = invp(kf);
        v = beta * w1[(i * 128 + k) * 128 + n] + ((k == n) ? (1.0f - beta) : 0.0f);
    } else {
        int k2 = invp(kf - 128);
        v = 0.5f * (beta * w2[(i * 128 + k2) * 128 + n] + ((k2 == n) ? (1.0f - beta) : 0.0f));
    }
    Wp[idx] = f2b(v);
}

// ---------------- lin1 (MFMA): h0 -> abuf[:,128:256) bf16 packed ----------------
__global__ __launch_bounds__(256) void k_lin1m(const float* __restrict__ x,
                                               const float* __restrict__ W,
                                               const float* __restrict__ b,
                                               unsigned short* __restrict__ abuf) {
    __shared__ __attribute__((aligned(16))) unsigned short Bs[8192];
    int t = threadIdx.x;
    for (int idx = t; idx < 8192; idx += 256) {
        int s = idx >> 12;
        int tt = (idx >> 9) & 7;
        int lane = (idx >> 3) & 63;
        int j = idx & 7;
        int k = s * 32 + (lane >> 4) * 8 + j;
        int n = tt * 16 + (lane & 15);
        Bs[idx] = f2b(W[k * 128 + n]);
    }
    __syncthreads();

    int w = t >> 6, lane = t & 63;
    int q = lane >> 4, r = lane & 15;
    int m0 = blockIdx.x * 64 + w * 16;
    int mA = m0 + r; if (mA > NNODES - 1) mA = NNODES - 1;
    const float* xrow = x + (size_t)mA * 64;

    f32x4 acc[8];
#pragma unroll
    for (int tt = 0; tt < 8; ++tt) {
        float bv = b[tt * 16 + r];
        acc[tt] = (f32x4){bv, bv, bv, bv};
    }
#pragma unroll
    for (int s = 0; s < 2; ++s) {
        float xv[8];
        *(float4*)&xv[0] = *(const float4*)(xrow + s * 32 + q * 8);
        *(float4*)&xv[4] = *(const float4*)(xrow + s * 32 + q * 8 + 4);
        bhalf8 ah, al;
#pragma unroll
        for (int j = 0; j < 8; ++j) {
            unsigned short hb = f2b(xv[j]);
            ah[j] = (short)hb;
            al[j] = (short)f2b(xv[j] - b2f(hb));
        }
#pragma unroll
        for (int tt = 0; tt < 8; ++tt) {
            bhalf8 bf = *(const bhalf8*)&Bs[((s * 8 + tt) << 9) + lane * 8];
            acc[tt] = __builtin_amdgcn_mfma_f32_16x16x32_bf16(ah, bf, acc[tt], 0, 0, 0);
            acc[tt] = __builtin_amdgcn_mfma_f32_16x16x32_bf16(al, bf, acc[tt], 0, 0, 0);
        }
    }
#pragma unroll
    for (int i = 0; i < 4; ++i) {
        int mm = m0 + q * 4 + i;
        if (mm < NNODES) {
            bhalf8 hv;
#pragma unroll
            for (int tt = 0; tt < 8; ++tt) hv[tt] = (short)f2b(acc[tt][i]);
            *(bhalf8*)&abuf[(size_t)mm * 256 + 128 + 8 * r] = hv;
        }
    }
}

// ---------------- SpMM: padded CSR (x8), 32-bit byte-offset gathers ----------------
template <int U8>
__global__ __launch_bounds__(256) void k_spmm9(const unsigned char* __restrict__ srcu,
                                               const float* __restrict__ qs,
                                               const unsigned char* __restrict__ srcb,
                                               const int* __restrict__ offs,
                                               const int2* __restrict__ csr,
                                               const float* __restrict__ dinv,
                                               unsigned short* __restrict__ abuf) {
    int gt = blockIdx.x * 256 + threadIdx.x;
    int c = gt >> 5;          // node (2 per wave)
    unsigned s = threadIdx.x & 31;  // packed dims [4s, 4s+4)
    if (c >= NNODES) return;
    unsigned s4 = s * 4, s8 = s * 8;
    float di = dinv[c];
    float dw = di * di;
    float acc0, acc1, acc2, acc3;
    if (U8) {
        unsigned a = *(const unsigned*)(srcu + (((unsigned)c << 7) + s4));
        float dws = dw * qs[c];
        acc0 = dws * ub(a, 0); acc1 = dws * ub(a, 1);
        acc2 = dws * ub(a, 2); acc3 = dws * ub(a, 3);
    } else {
        uint2 g = *(const uint2*)(srcb + (((unsigned)c << 9) + s8));
        acc0 = dw * b2f_lo(g.x); acc1 = dw * b2f_hi(g.x);
        acc2 = dw * b2f_lo(g.y); acc3 = dw * b2f_hi(g.y);
    }
    int e = offs[c], e1 = offs[c + 1];  // multiples of 8; pads have w=0
    for (; e < e1; e += 8) {
        int2 E[8];
#pragma unroll
        for (int u = 0; u < 8; ++u) E[u] = csr[e + u];
        if (U8) {
            unsigned a[8];
            float wv[8];
#pragma unroll
            for (int u = 0; u < 8; ++u) {
                wv[u] = __builtin_bit_cast(float, E[u].y) * qs[E[u].x];
                a[u] = *(const unsigned*)(srcu + (((unsigned)E[u].x << 7) + s4));
            }
#pragma unroll
            for (int u = 0; u < 8; ++u) {
                acc0 = fmaf(wv[u], ub(a[u], 0), acc0);
                acc1 = fmaf(wv[u], ub(a[u], 1), acc1);
                acc2 = fmaf(wv[u], ub(a[u], 2), acc2);
                acc3 = fmaf(wv[u], ub(a[u], 3), acc3);
            }
        } else {
            uint2 g[8];
#pragma unroll
            for (int u = 0; u < 8; ++u)
                g[u] = *(const uint2*)(srcb + (((unsigned)E[u].x << 9) + s8));
#pragma unroll
            for (int u = 0; u < 8; ++u) {
                float wv = __builtin_bit_cast(float, E[u].y);
                acc0 = fmaf(wv, b2f_lo(g[u].x), acc0);
                acc1 = fmaf(wv, b2f_hi(g[u].x), acc1);
                acc2 = fmaf(wv, b2f_lo(g[u].y), acc2);
                acc3 = fmaf(wv, b2f_hi(g[u].y), acc3);
            }
        }
    }
    uint2 outv;
    outv.x = (unsigned)f2b(0.5f * acc0) | ((unsigned)f2b(0.5f * acc1) << 16);
    outv.y = (unsigned)f2b(0.5f * acc2) | ((unsigned)f2b(0.5f * acc3) << 16);
    *(uint2*)((unsigned char*)abuf + (((unsigned)c << 9) + s8)) = outv;
}

// ---------------- layer GEMM v11: gemm10 core + fused epilogue via light spin ----
// MODE 1: + actq for own 64 rows. MODE 2: + lin2 for own 64 rows.
// Residency guarantee (spin cannot deadlock): __launch_bounds__(256,4) caps VGPR
// at 128 -> 4 blocks/CU; LDS 33.8KB -> 4 blocks/CU; 4*256=1024 >= 782 blocks.
// Spin: ONE poller per block (t0), s_sleep, relaxed loads; release-add posts this
// block's outb/pstat stores (pattern validated for correctness in round 4).
template <int MODE>
__global__ __launch_bounds__(256, 4) void k_gemm11(const unsigned short* __restrict__ A,
                                                   const unsigned short* __restrict__ Bp,
                                                   unsigned short* __restrict__ outb,
                                                   float* __restrict__ pstat,
                                                   int* __restrict__ lcnt,
                                                   const float* __restrict__ nw,
                                                   const float* __restrict__ nb,
                                                   unsigned char* __restrict__ hact,
                                                   float* __restrict__ qs,
                                                   const float* __restrict__ l2w,
                                                   const float* __restrict__ l2b,
                                                   float* __restrict__ out) {
    __shared__ __attribute__((aligned(16))) unsigned short Bs[16384];  // 32 KB
    __shared__ float wred[8];
    __shared__ float sk2[128], ck2[128];
    int t = threadIdx.x;
    int bx = blockIdx.x;
    int mt = bx >> 1, nh = bx & 1;
#pragma unroll
    for (int it = 0; it < 8; ++it) {
        int o = it * 2048 + t * 8;
        int g = o >> 9;
        int s = g >> 2, ntl = g & 3;
        int src = (((s * 8) + ntl + 4 * nh) << 9) + (o & 511);
        *(bhalf8*)&Bs[o] = *(const bhalf8*)&Bp[src];
    }

    int w = t >> 6, lane = t & 63;
    int q = lane >> 4, r = lane & 15;
    float ps1 = 0.f, ps2 = 0.f;

    // issue BOTH sub-tiles' A loads before the barrier
    int m0a = mt * 128 + w * 16;
    int m0b = m0a + 64;
    int mAa = m0a + r; if (mAa > NNODES - 1) mAa = NNODES - 1;
    int mAb = m0b + r; if (mAb > NNODES - 1) mAb = NNODES - 1;
    const unsigned short* ra = A + (size_t)mAa * 256;
    const unsigned short* rb = A + (size_t)mAb * 256;
    bhalf8 af0[8], af1[8];
#pragma unroll
    for (int s = 0; s < 8; ++s) af0[s] = *(const bhalf8*)(ra + s * 32 + q * 8);
#pragma unroll
    for (int s = 0; s < 8; ++s) af1[s] = *(const bhalf8*)(rb + s * 32 + q * 8);

    __syncthreads();  // Bs ready

    // ---- sub 0 ----
    {
        f32x4 acc[4];
#pragma unroll
        for (int i = 0; i < 4; ++i) acc[i] = (f32x4){0.f, 0.f, 0.f, 0.f};
#pragma unroll
        for (int s = 0; s < 8; ++s) {
#pragma unroll
            for (int ntl = 0; ntl < 4; ++ntl) {
                bhalf8 bfr = *(const bhalf8*)&Bs[((s * 4 + ntl) << 9) + lane * 8];
                acc[ntl] = __builtin_amdgcn_mfma_f32_16x16x32_bf16(af0[s], bfr, acc[ntl], 0, 0, 0);
            }
        }
#pragma unroll
        for (int i = 0; i < 4; ++i) {
            int mm = m0a + q * 4 + i;
            if (mm < NNODES) {
                unsigned lo = 0, hi = 0;
#pragma unroll
                for (int ntl = 0; ntl < 4; ++ntl) {
                    float v = acc[ntl][i];
                    ps1 += v; ps2 += v * v;
                    unsigned bits = (unsigned)f2b(v);
                    if (ntl < 2) lo |= bits << (16 * ntl);
                    else         hi |= bits << (16 * (ntl - 2));
                }
                *(uint2*)&outb[(size_t)mm * 128 + 8 * r + 4 * nh] = make_uint2(lo, hi);
            }
        }
    }
    // ---- sub 1 ----
    {
        f32x4 acc[4];
#pragma unroll
        for (int i = 0; i < 4; ++i) acc[i] = (f32x4){0.f, 0.f, 0.f, 0.f};
#pragma unroll
        for (int s = 0; s < 8; ++s) {
#pragma unroll
            for (int ntl = 0; ntl < 4; ++ntl) {
                bhalf8 bfr = *(const bhalf8*)&Bs[((s * 4 + ntl) << 9) + lane * 8];
                acc[ntl] = __builtin_amdgcn_mfma_f32_16x16x32_bf16(af1[s], bfr, acc[ntl], 0, 0, 0);
            }
        }
#pragma unroll
        for (int i = 0; i < 4; ++i) {
            int mm = m0b + q * 4 + i;
            if (mm < NNODES) {
                unsigned lo = 0, hi = 0;
#pragma unroll
                for (int ntl = 0; ntl < 4; ++ntl) {
                    float v = acc[ntl][i];
                    ps1 += v; ps2 += v * v;
                    unsigned bits = (unsigned)f2b(v);
                    if (ntl < 2) lo |= bits << (16 * ntl);
                    else         hi |= bits << (16 * (ntl - 2));
                }
                *(uint2*)&outb[(size_t)mm * 128 + 8 * r + 4 * nh] = make_uint2(lo, hi);
            }
        }
    }
    // ---- stats: wave shfl-reduce, one store per block, then light spin barrier ----
#pragma unroll
    for (int o = 1; o < 64; o <<= 1) {
        ps1 += __shfl_xor(ps1, o);
        ps2 += __shfl_xor(ps2, o);
    }
    if (lane == 0) { wred[w] = ps1; wred[4 + w] = ps2; }
    __syncthreads();  // wred ready AND all outb stores issued by all threads
    if (t == 0) {
        pstat[bx] = wred[0] + wred[1] + wred[2] + wred[3];
        pstat[NPST + bx] = wred[4] + wred[5] + wred[6] + wred[7];
        // release: L2 writeback of this XCD's dirty lines (incl. outb) + post
        __hip_atomic_fetch_add(lcnt, 1, __ATOMIC_RELEASE, __HIP_MEMORY_SCOPE_AGENT);
        while (__hip_atomic_load(lcnt, __ATOMIC_RELAXED, __HIP_MEMORY_SCOPE_AGENT) < NPST)
            __builtin_amdgcn_s_sleep(8);
    }
    __syncthreads();
    __builtin_amdgcn_fence(__ATOMIC_ACQUIRE, "agent");

    // ---- global stats from pstat (dead Bs reused as reduction scratch) ----
    float* rr = (float*)Bs;
    float s1 = 0.f, s2 = 0.f;
    for (int k = t; k < NPST; k += 256) { s1 += pstat[k]; s2 += pstat[NPST + k]; }
    rr[t] = s1; rr[256 + t] = s2;
    __syncthreads();
    for (int o = 128; o > 0; o >>= 1) {
        if (t < o) { rr[t] += rr[t + o]; rr[256 + t] += rr[256 + t + o]; }
        __syncthreads();
    }
    const float Mf = (float)NNODES * 128.0f;
    float mean = rr[0] / Mf;
    float var = rr[256] / Mf - mean * mean;
    float inv = 1.0f / (sqrtf(fmaxf(var, 0.0f)) + 1e-5f);
    __syncthreads();  // rr reads done before any Bs reuse

    if (MODE == 1) {
        // ---- actq for own 64 rows [bx*64, bx*64+64) ----
        if (t < 128) {
            int d = invp(t);
            float sk = inv * nw[d];
            sk2[t] = sk;
            ck2[t] = nb[d] - mean * sk;
        }
        __syncthreads();
        int sl = t & 31;
        int r0 = bx * 64;
#pragma unroll 1
        for (int ii = 0; ii < 8; ++ii) {
            int row = r0 + ii * 8 + (t >> 5);
            if (row < NNODES) {
                uint2 g = *(const uint2*)(outb + (size_t)row * 128 + sl * 4);
                float h[4];
                h[0] = fmaxf(fmaf(b2f_lo(g.x), sk2[4 * sl + 0], ck2[4 * sl + 0]), 0.0f);
                h[1] = fmaxf(fmaf(b2f_hi(g.x), sk2[4 * sl + 1], ck2[4 * sl + 1]), 0.0f);
                h[2] = fmaxf(fmaf(b2f_lo(g.y), sk2[4 * sl + 2], ck2[4 * sl + 2]), 0.0f);
                h[3] = fmaxf(fmaf(b2f_hi(g.y), sk2[4 * sl + 3], ck2[4 * sl + 3]), 0.0f);
                float rmax = fmaxf(fmaxf(h[0], h[1]), fmaxf(h[2], h[3]));
#pragma unroll
                for (int o = 1; o < 32; o <<= 1) rmax = fmaxf(rmax, __shfl_xor(rmax, o));
                float rs = (rmax > 0.f) ? 255.0f / rmax : 0.0f;
                unsigned pk = 0;
#pragma unroll
                for (int k = 0; k < 4; ++k) {
                    float a = fminf(h[k] * rs, 255.0f);
                    pk |= __float2uint_rn(a) << (8 * k);
                }
                *(unsigned*)(hact + (size_t)row * 128 + sl * 4) = pk;
                if (sl == 0) qs[row] = (rmax > 0.f) ? rmax * (1.0f / 255.0f) : 0.0f;
            }
        }
    }
    if (MODE == 2) {
        // ---- lin2 (final LN+ReLU -> MFMA) for own 64 rows [bx*64, +64) ----
        for (int idx = t; idx < 8192; idx += 256) {
            int s = idx >> 11;
            int tt = (idx >> 9) & 3;
            int ln = (idx >> 3) & 63;
            int j = idx & 7;
            int kf = s * 32 + (ln >> 4) * 8 + j;
            int k = invp(kf);
            int n = tt * 16 + (ln & 15);
            Bs[idx] = f2b(l2w[k * 64 + n]);
        }
        if (t < 128) {
            int d = invp(t);
            float sk = inv * nw[d];
            sk2[t] = sk;
            ck2[t] = nb[d] - mean * sk;
        }
        __syncthreads();
        int m0 = bx * 64 + w * 16;
        int mA = m0 + r; if (mA > NNODES - 1) mA = NNODES - 1;
        const unsigned short* arow = outb + (size_t)mA * 128;
        f32x4 acc2[4];
#pragma unroll
        for (int tt = 0; tt < 4; ++tt) {
            float bv = l2b[tt * 16 + r];
            acc2[tt] = (f32x4){bv, bv, bv, bv};
        }
#pragma unroll
        for (int s = 0; s < 4; ++s) {
            bhalf8 raw = *(const bhalf8*)(arow + s * 32 + q * 8);
            bhalf8 af;
#pragma unroll
            for (int j = 0; j < 8; ++j) {
                int ppos = s * 32 + q * 8 + j;
                float v = b2f((unsigned short)raw[j]);
                v = fmaxf(fmaf(v, sk2[ppos], ck2[ppos]), 0.0f);
                af[j] = (short)f2b(v);
            }
#pragma unroll
            for (int tt = 0; tt < 4; ++tt) {
                bhalf8 bf = *(const bhalf8*)&Bs[((s * 4 + tt) << 9) + lane * 8];
                acc2[tt] = __builtin_amdgcn_mfma_f32_16x16x32_bf16(af, bf, acc2[tt], 0, 0, 0);
            }
        }
#pragma unroll
        for (int i = 0; i < 4; ++i) {
            int mm = m0 + q * 4 + i;
            if (mm < NNODES) {
#pragma unroll
                for (int tt = 0; tt < 4; ++tt)
                    out[(size_t)mm * 64 + tt * 16 + r] = acc2[tt][i];
            }
        }
    }
}

// ---------------- launch ----------------

extern "C" void kernel_launch(void* const* d_in, const int* in_sizes, int n_in,
                              void* d_out, int out_size, void* d_ws, size_t ws_size,
                              hipStream_t stream) {
    const float* x      = (const float*)d_in[0];
    const int*   ei     = (const int*)d_in[1];
    const float* lin1_w = (const float*)d_in[2];
    const float* lin1_b = (const float*)d_in[3];
    const float* w1     = (const float*)d_in[4];
    const float* w2     = (const float*)d_in[5];
    const float* norm_w = (const float*)d_in[6];
    const float* norm_b = (const float*)d_in[7];
    const float* lin2_w = (const float*)d_in[8];
    const float* lin2_b = (const float*)d_in[9];
    float* out = (float*)d_out;

    const int* row = ei;
    const int* col = ei + NEDGES;

    char* p = (char*)d_ws;
    auto take = [&](size_t bytes) -> char* {
        char* r = p;
        p += (bytes + 255) & ~(size_t)255;
        return r;
    };
    unsigned short* abuf = (unsigned short*)take((size_t)NNODES * 256 * 2);  // [agg|h0] bf16 packed
    unsigned short* outb = (unsigned short*)take((size_t)NNODES * 128 * 2);  // layer out bf16 packed
    unsigned char*  hact = (unsigned char*)take((size_t)NNODES * 128);       // activated u8
    float*          qs   = (float*)take((size_t)NNODES * 4);                 // per-row dequant scale
    unsigned short* Wp   = (unsigned short*)take((size_t)NLAYERS * 32768 * 2);
    float* dinv    = (float*)take((size_t)NNODES * 4);
    float* pstat   = (float*)take((size_t)2 * NPST * 4);                     // per-block stats partials
    // contiguous zero-init zone: counts | cursor | lcnt[8 @64B] | csr (one memset)
    size_t zhead = (size_t)NNODES * 4 * 2 + 1024;
    size_t zhead_al = (zhead + 255) & ~(size_t)255;
    char* zzone    = take(zhead_al + (size_t)CSRMAX * 8);
    int*   counts  = (int*)zzone;
    int*   cursor  = (int*)(zzone + (size_t)NNODES * 4);
    int*   lcnt    = (int*)(zzone + (size_t)NNODES * 4 * 2);  // layer i at lcnt[16*i]
    int2*  csr     = (int2*)(zzone + zhead_al);
    int*   offs    = (int*)take((size_t)(NNODES + 1) * 4);
    int*   part    = (int*)take((size_t)NSCANB * 4);

    hipMemsetAsync(zzone, 0, zhead_al + (size_t)CSRMAX * 8, stream);  // pads = {row 0, w 0}

    k_count<<<(NEDGES + 255) / 256, 256, 0, stream>>>(col, counts);
    k_dinv_bsum<<<NSCANB, 256, 0, stream>>>(counts, dinv, part);
    k_pscan<<<1, 256, 0, stream>>>(part);
    k_offs<<<NSCANB, 256, 0, stream>>>(counts, part, offs);
    k_scatter<<<(NEDGES + 255) / 256, 256, 0, stream>>>(row, col, offs, cursor, dinv, csr);
    k_wcp2<<<(NLAYERS * 32768 + 255) / 256, 256, 0, stream>>>(w1, w2, Wp);
    k_lin1m<<<(NNODES + 63) / 64, 256, 0, stream>>>(x, lin1_w, lin1_b, abuf);

    for (int i = 0; i < NLAYERS; ++i) {
        if (i == 0) {
            k_spmm9<0><<<(NNODES * 32 + 255) / 256, 256, 0, stream>>>(
                nullptr, nullptr, (const unsigned char*)(abuf + 128), offs, csr, dinv, abuf);
        } else {
            k_spmm9<1><<<(NNODES * 32 + 255) / 256, 256, 0, stream>>>(
                hact, qs, nullptr, offs, csr, dinv, abuf);
        }
        if (i < NLAYERS - 1) {
            k_gemm11<1><<<NPST, 256, 0, stream>>>(abuf, Wp + (size_t)i * 32768,
                                                  outb, pstat, lcnt + 16 * i,
                                                  norm_w + (size_t)i * 128,
                                                  norm_b + (size_t)i * 128,
                                                  hact, qs, nullptr, nullptr, nullptr);
        } else {
            k_gemm11<2><<<NPST, 256, 0, stream>>>(abuf, Wp + (size_t)i * 32768,
                                                  outb, pstat, lcnt + 16 * i,
                                                  norm_w + 7 * 128, norm_b + 7 * 128,
                                                  nullptr, nullptr, lin2_w, lin2_b, out);
        }
    }
}

// Round 10
// 536.779 us; speedup vs baseline: 2.6271x; 2.6271x over previous
//
#include <hip/hip_runtime.h>
#include <hip/hip_bf16.h>
#include <math.h>

#define NNODES 50000
#define NEDGES 500000
#define NLAYERS 8
#define NSCANB 196  // ceil(NNODES/256)
#define CSRMAX (NEDGES + 7 * NNODES)  // padded-to-8 worst case
#define NPST 782    // 391 m-tiles x 2 n-halves = gemm blocks = stat slots

typedef __attribute__((ext_vector_type(8))) short bhalf8;
typedef __attribute__((ext_vector_type(4))) float f32x4;

// K-dim permutation: packed pos p <-> natural dim d = 16*(p&7) + (p>>3).
static __device__ __forceinline__ int invp(int p) { return 16 * (p & 7) + (p >> 3); }

static __device__ __forceinline__ unsigned short f2b(float v) {
    unsigned u = __builtin_bit_cast(unsigned, v);
    u += 0x7fffu + ((u >> 16) & 1u);
    return (unsigned short)(u >> 16);
}
static __device__ __forceinline__ float b2f(unsigned short w) {
    return __builtin_bit_cast(float, (unsigned)w << 16);
}
static __device__ __forceinline__ float b2f_lo(unsigned w) {
    return __builtin_bit_cast(float, w << 16);
}
static __device__ __forceinline__ float b2f_hi(unsigned w) {
    return __builtin_bit_cast(float, w & 0xffff0000u);
}
static __device__ __forceinline__ float ub(unsigned a, int k) {
    return (float)((a >> (8 * k)) & 0xffu);  // folds to v_cvt_f32_ubyteN
}

// ---------------- graph preprocessing ----------------

__global__ void k_count(const int* __restrict__ col, int* __restrict__ counts) {
    int e = blockIdx.x * 256 + threadIdx.x;
    if (e < NEDGES) atomicAdd(&counts[col[e]], 1);
}

// fused dinv + 2-level exclusive scan of padded counts (replaces 3 kernels).
// 196 blocks all resident; ONE poller per block (t==0); tiny working set so the
// agent-scope fence's L2 cost is negligible here (unlike the 782-block gemm case).
__global__ __launch_bounds__(256) void k_scan196(const int* __restrict__ counts,
                                                 float* __restrict__ dinv,
                                                 int* __restrict__ part,
                                                 int* __restrict__ pcnt,
                                                 int* __restrict__ offs) {
    __shared__ int ls[256];
    int t = threadIdx.x, bx = blockIdx.x, i = bx * 256 + t;
    int cnt = (i < NNODES) ? counts[i] : 0;
    if (i < NNODES) dinv[i] = rsqrtf((float)(cnt + 1));
    int v = (i < NNODES) ? ((cnt + 7) & ~7) : 0;
    ls[t] = v;
    __syncthreads();
    for (int o = 1; o < 256; o <<= 1) {
        int x = (t >= o) ? ls[t - o] : 0;
        __syncthreads();
        ls[t] += x;
        __syncthreads();
    }
    int lsum = ls[255];
    int lexcl = ls[t] - v;
    __syncthreads();  // all ls reads done before reuse
    if (t == 0) {
        __hip_atomic_store(&part[bx], lsum, __ATOMIC_RELAXED, __HIP_MEMORY_SCOPE_AGENT);
        __hip_atomic_fetch_add(pcnt, 1, __ATOMIC_RELEASE, __HIP_MEMORY_SCOPE_AGENT);
        while (__hip_atomic_load(pcnt, __ATOMIC_RELAXED, __HIP_MEMORY_SCOPE_AGENT) < NSCANB)
            __builtin_amdgcn_s_sleep(2);
    }
    __syncthreads();
    __builtin_amdgcn_fence(__ATOMIC_ACQUIRE, "agent");
    int pv = (t < NSCANB && t < bx)
                 ? __hip_atomic_load(&part[t], __ATOMIC_RELAXED, __HIP_MEMORY_SCOPE_AGENT)
                 : 0;
    ls[t] = pv;
    __syncthreads();
    for (int o = 128; o > 0; o >>= 1) {
        if (t < o) ls[t] += ls[t + o];
        __syncthreads();
    }
    int excl = ls[0] + lexcl;
    if (i < NNODES) offs[i] = excl;
    if (i == NNODES - 1) offs[NNODES] = excl + v;
}

// csr pre-memset to 0 -> pad entries are {row 0, w 0.0f}
__global__ void k_scatter(const int* __restrict__ row, const int* __restrict__ col,
                          const int* __restrict__ offs, int* __restrict__ cursor,
                          const float* __restrict__ dinv, int2* __restrict__ csr) {
    int e = blockIdx.x * 256 + threadIdx.x;
    if (e < NEDGES) {
        int c = col[e], r = row[e];
        int pos = offs[c] + atomicAdd(&cursor[c], 1);
        float w = dinv[r] * dinv[c];
        csr[pos] = make_int2(r, __builtin_bit_cast(int, w));
    }
}

// ---------------- folded + packed layer weights (K-permuted) ----------------
__global__ void k_wcp2(const float* __restrict__ w1, const float* __restrict__ w2,
                       unsigned short* __restrict__ Wp) {
    int idx = blockIdx.x * 256 + threadIdx.x;
    if (idx >= NLAYERS * 32768) return;
    int i = idx >> 15;
    int rem = idx & 32767;
    int s = rem >> 12;
    int t = (rem >> 9) & 7;
    int lane = (rem >> 3) & 63;
    int j = rem & 7;
    int kf = s * 32 + (lane >> 4) * 8 + j;
    int n = t * 16 + (lane & 15);
    float beta = logf(1.0f / (float)(i + 1) + 1.0f);
    float v;
    if (kf < 128) {
        int k = invp(kf);
        v = beta * w1[(i * 128 + k) * 128 + n] + ((k == n) ? (1.0f - beta) : 0.0f);
    } else {
        int k2 = invp(kf - 128);
        v = 0.5f * (beta * w2[(i * 128 + k2) * 128 + n] + ((k2 == n) ? (1.0f - beta) : 0.0f));
    }
    Wp[idx] = f2b(v);
}

// ---------------- lin1 (MFMA): h0 -> abuf[:,128:256) bf16 packed ----------------
__global__ __launch_bounds__(256) void k_lin1m(const float* __restrict__ x,
                                               const float* __restrict__ W,
                                               const float* __restrict__ b,
                                               unsigned short* __restrict__ abuf) {
    __shared__ __attribute__((aligned(16))) unsigned short Bs[8192];
    int t = threadIdx.x;
    for (int idx = t; idx < 8192; idx += 256) {
        int s = idx >> 12;
        int tt = (idx >> 9) & 7;
        int lane = (idx >> 3) & 63;
        int j = idx & 7;
        int k = s * 32 + (lane >> 4) * 8 + j;
        int n = tt * 16 + (lane & 15);
        Bs[idx] = f2b(W[k * 128 + n]);
    }
    __syncthreads();

    int w = t >> 6, lane = t & 63;
    int q = lane >> 4, r = lane & 15;
    int m0 = blockIdx.x * 64 + w * 16;
    int mA = m0 + r; if (mA > NNODES - 1) mA = NNODES - 1;
    const float* xrow = x + (size_t)mA * 64;

    f32x4 acc[8];
#pragma unroll
    for (int tt = 0; tt < 8; ++tt) {
        float bv = b[tt * 16 + r];
        acc[tt] = (f32x4){bv, bv, bv, bv};
    }
#pragma unroll
    for (int s = 0; s < 2; ++s) {
        float xv[8];
        *(float4*)&xv[0] = *(const float4*)(xrow + s * 32 + q * 8);
        *(float4*)&xv[4] = *(const float4*)(xrow + s * 32 + q * 8 + 4);
        bhalf8 ah, al;
#pragma unroll
        for (int j = 0; j < 8; ++j) {
            unsigned short hb = f2b(xv[j]);
            ah[j] = (short)hb;
            al[j] = (short)f2b(xv[j] - b2f(hb));
        }
#pragma unroll
        for (int tt = 0; tt < 8; ++tt) {
            bhalf8 bf = *(const bhalf8*)&Bs[((s * 8 + tt) << 9) + lane * 8];
            acc[tt] = __builtin_amdgcn_mfma_f32_16x16x32_bf16(ah, bf, acc[tt], 0, 0, 0);
            acc[tt] = __builtin_amdgcn_mfma_f32_16x16x32_bf16(al, bf, acc[tt], 0, 0, 0);
        }
    }
#pragma unroll
    for (int i = 0; i < 4; ++i) {
        int mm = m0 + q * 4 + i;
        if (mm < NNODES) {
            bhalf8 hv;
#pragma unroll
            for (int tt = 0; tt < 8; ++tt) hv[tt] = (short)f2b(acc[tt][i]);
            *(bhalf8*)&abuf[(size_t)mm * 256 + 128 + 8 * r] = hv;
        }
    }
}

// ---------------- SpMM: padded CSR (x8), 32-bit byte-offset gathers ----------------
template <int U8>
__global__ __launch_bounds__(256) void k_spmm9(const unsigned char* __restrict__ srcu,
                                               const float* __restrict__ qs,
                                               const unsigned char* __restrict__ srcb,
                                               const int* __restrict__ offs,
                                               const int2* __restrict__ csr,
                                               const float* __restrict__ dinv,
                                               unsigned short* __restrict__ abuf) {
    int gt = blockIdx.x * 256 + threadIdx.x;
    int c = gt >> 5;          // node (2 per wave)
    unsigned s = threadIdx.x & 31;  // packed dims [4s, 4s+4)
    if (c >= NNODES) return;
    unsigned s4 = s * 4, s8 = s * 8;
    float di = dinv[c];
    float dw = di * di;
    float acc0, acc1, acc2, acc3;
    if (U8) {
        unsigned a = *(const unsigned*)(srcu + (((unsigned)c << 7) + s4));
        float dws = dw * qs[c];
        acc0 = dws * ub(a, 0); acc1 = dws * ub(a, 1);
        acc2 = dws * ub(a, 2); acc3 = dws * ub(a, 3);
    } else {
        uint2 g = *(const uint2*)(srcb + (((unsigned)c << 9) + s8));
        acc0 = dw * b2f_lo(g.x); acc1 = dw * b2f_hi(g.x);
        acc2 = dw * b2f_lo(g.y); acc3 = dw * b2f_hi(g.y);
    }
    int e = offs[c], e1 = offs[c + 1];  // multiples of 8; pads have w=0
    for (; e < e1; e += 8) {
        int2 E[8];
#pragma unroll
        for (int u = 0; u < 8; ++u) E[u] = csr[e + u];
        if (U8) {
            unsigned a[8];
            float wv[8];
#pragma unroll
            for (int u = 0; u < 8; ++u) {
                wv[u] = __builtin_bit_cast(float, E[u].y) * qs[E[u].x];
                a[u] = *(const unsigned*)(srcu + (((unsigned)E[u].x << 7) + s4));
            }
#pragma unroll
            for (int u = 0; u < 8; ++u) {
                acc0 = fmaf(wv[u], ub(a[u], 0), acc0);
                acc1 = fmaf(wv[u], ub(a[u], 1), acc1);
                acc2 = fmaf(wv[u], ub(a[u], 2), acc2);
                acc3 = fmaf(wv[u], ub(a[u], 3), acc3);
            }
        } else {
            uint2 g[8];
#pragma unroll
            for (int u = 0; u < 8; ++u)
                g[u] = *(const uint2*)(srcb + (((unsigned)E[u].x << 9) + s8));
#pragma unroll
            for (int u = 0; u < 8; ++u) {
                float wv = __builtin_bit_cast(float, E[u].y);
                acc0 = fmaf(wv, b2f_lo(g[u].x), acc0);
                acc1 = fmaf(wv, b2f_hi(g[u].x), acc1);
                acc2 = fmaf(wv, b2f_lo(g[u].y), acc2);
                acc3 = fmaf(wv, b2f_hi(g[u].y), acc3);
            }
        }
    }
    uint2 outv;
    outv.x = (unsigned)f2b(0.5f * acc0) | ((unsigned)f2b(0.5f * acc1) << 16);
    outv.y = (unsigned)f2b(0.5f * acc2) | ((unsigned)f2b(0.5f * acc3) << 16);
    *(uint2*)((unsigned char*)abuf + (((unsigned)c << 9) + s8)) = outv;
}

// ---------------- layer GEMM v10: M=128 x N=64, atomic-free stats, A prefetch ----
// grid = 391*2 = 782 blocks: mt = bx>>1, nh = bx&1. Proven 22us/layer (round 8):
//  (a) per-block stats via wave shfl-reduce + ONE plain store to pstat[bx];
//  (b) both sub-tiles' A fragments issued before the B barrier;
//  (c) 782 blocks, all resident at 4 blocks/CU.
__global__ __launch_bounds__(256) void k_gemm10(const unsigned short* __restrict__ A,
                                                const unsigned short* __restrict__ Bp,
                                                unsigned short* __restrict__ outb,
                                                float* __restrict__ pstat) {
    __shared__ __attribute__((aligned(16))) unsigned short Bs[16384];  // 32 KB
    __shared__ float wred[8];
    int t = threadIdx.x;
    int mt = blockIdx.x >> 1, nh = blockIdx.x & 1;
#pragma unroll
    for (int it = 0; it < 8; ++it) {
        int o = it * 2048 + t * 8;
        int g = o >> 9;
        int s = g >> 2, ntl = g & 3;
        int src = (((s * 8) + ntl + 4 * nh) << 9) + (o & 511);
        *(bhalf8*)&Bs[o] = *(const bhalf8*)&Bp[src];
    }

    int w = t >> 6, lane = t & 63;
    int q = lane >> 4, r = lane & 15;
    float ps1 = 0.f, ps2 = 0.f;

    // issue BOTH sub-tiles' A loads before the barrier (overlap B-fill + sub0 MFMA)
    int m0a = mt * 128 + w * 16;
    int m0b = m0a + 64;
    int mAa = m0a + r; if (mAa > NNODES - 1) mAa = NNODES - 1;
    int mAb = m0b + r; if (mAb > NNODES - 1) mAb = NNODES - 1;
    const unsigned short* ra = A + (size_t)mAa * 256;
    const unsigned short* rb = A + (size_t)mAb * 256;
    bhalf8 af0[8], af1[8];
#pragma unroll
    for (int s = 0; s < 8; ++s) af0[s] = *(const bhalf8*)(ra + s * 32 + q * 8);
#pragma unroll
    for (int s = 0; s < 8; ++s) af1[s] = *(const bhalf8*)(rb + s * 32 + q * 8);

    __syncthreads();  // Bs ready

    // ---- sub 0 ----
    {
        f32x4 acc[4];
#pragma unroll
        for (int i = 0; i < 4; ++i) acc[i] = (f32x4){0.f, 0.f, 0.f, 0.f};
#pragma unroll
        for (int s = 0; s < 8; ++s) {
#pragma unroll
            for (int ntl = 0; ntl < 4; ++ntl) {
                bhalf8 bfr = *(const bhalf8*)&Bs[((s * 4 + ntl) << 9) + lane * 8];
                acc[ntl] = __builtin_amdgcn_mfma_f32_16x16x32_bf16(af0[s], bfr, acc[ntl], 0, 0, 0);
            }
        }
#pragma unroll
        for (int i = 0; i < 4; ++i) {
            int mm = m0a + q * 4 + i;
            if (mm < NNODES) {
                unsigned lo = 0, hi = 0;
#pragma unroll
                for (int ntl = 0; ntl < 4; ++ntl) {
                    float v = acc[ntl][i];
                    ps1 += v; ps2 += v * v;
                    unsigned bits = (unsigned)f2b(v);
                    if (ntl < 2) lo |= bits << (16 * ntl);
                    else         hi |= bits << (16 * (ntl - 2));
                }
                *(uint2*)&outb[(size_t)mm * 128 + 8 * r + 4 * nh] = make_uint2(lo, hi);
            }
        }
    }
    // ---- sub 1 ----
    {
        f32x4 acc[4];
#pragma unroll
        for (int i = 0; i < 4; ++i) acc[i] = (f32x4){0.f, 0.f, 0.f, 0.f};
#pragma unroll
        for (int s = 0; s < 8; ++s) {
#pragma unroll
            for (int ntl = 0; ntl < 4; ++ntl) {
                bhalf8 bfr = *(const bhalf8*)&Bs[((s * 4 + ntl) << 9) + lane * 8];
                acc[ntl] = __builtin_amdgcn_mfma_f32_16x16x32_bf16(af1[s], bfr, acc[ntl], 0, 0, 0);
            }
        }
#pragma unroll
        for (int i = 0; i < 4; ++i) {
            int mm = m0b + q * 4 + i;
            if (mm < NNODES) {
                unsigned lo = 0, hi = 0;
#pragma unroll
                for (int ntl = 0; ntl < 4; ++ntl) {
                    float v = acc[ntl][i];
                    ps1 += v; ps2 += v * v;
                    unsigned bits = (unsigned)f2b(v);
                    if (ntl < 2) lo |= bits << (16 * ntl);
                    else         hi |= bits << (16 * (ntl - 2));
                }
                *(uint2*)&outb[(size_t)mm * 128 + 8 * r + 4 * nh] = make_uint2(lo, hi);
            }
        }
    }
    // ---- stats: wave shfl-reduce, one plain store per block (no atomics) ----
#pragma unroll
    for (int o = 1; o < 64; o <<= 1) {
        ps1 += __shfl_xor(ps1, o);
        ps2 += __shfl_xor(ps2, o);
    }
    if (lane == 0) { wred[w] = ps1; wred[4 + w] = ps2; }
    __syncthreads();
    if (t == 0) {
        pstat[blockIdx.x] = wred[0] + wred[1] + wred[2] + wred[3];
        pstat[NPST + blockIdx.x] = wred[4] + wred[5] + wred[6] + wred[7];
    }
}

// ---------------- activation: reduce pstat -> LN+ReLU -> u8 quant ----------------
__global__ __launch_bounds__(256) void k_actq(const unsigned short* __restrict__ outb,
                                              const float* __restrict__ pstat,
                                              const float* __restrict__ nw,
                                              const float* __restrict__ nb,
                                              unsigned char* __restrict__ hact,
                                              float* __restrict__ qs) {
    __shared__ float rr[512];
    __shared__ float skp[128], ckp[128];
    int t = threadIdx.x;
    float s1 = 0.f, s2 = 0.f;
    for (int k = t; k < NPST; k += 256) { s1 += pstat[k]; s2 += pstat[NPST + k]; }
    rr[t] = s1; rr[256 + t] = s2;
    __syncthreads();
    for (int o = 128; o > 0; o >>= 1) {
        if (t < o) { rr[t] += rr[t + o]; rr[256 + t] += rr[256 + t + o]; }
        __syncthreads();
    }
    const float M = (float)NNODES * 128.0f;
    float mean = rr[0] / M;
    float var = rr[256] / M - mean * mean;
    float inv = 1.0f / (sqrtf(fmaxf(var, 0.0f)) + 1e-5f);
    if (t < 128) {
        int d = invp(t);
        float sk = inv * nw[d];
        skp[t] = sk;
        ckp[t] = nb[d] - mean * sk;
    }
    __syncthreads();
    int row = blockIdx.x * 8 + (t >> 5);
    int s = t & 31;
    if (row >= NNODES) return;
    uint2 g = *(const uint2*)(outb + (size_t)row * 128 + s * 4);
    float h[4];
    h[0] = fmaxf(fmaf(b2f_lo(g.x), skp[4 * s + 0], ckp[4 * s + 0]), 0.0f);
    h[1] = fmaxf(fmaf(b2f_hi(g.x), skp[4 * s + 1], ckp[4 * s + 1]), 0.0f);
    h[2] = fmaxf(fmaf(b2f_lo(g.y), skp[4 * s + 2], ckp[4 * s + 2]), 0.0f);
    h[3] = fmaxf(fmaf(b2f_hi(g.y), skp[4 * s + 3], ckp[4 * s + 3]), 0.0f);
    float rmax = fmaxf(fmaxf(h[0], h[1]), fmaxf(h[2], h[3]));
#pragma unroll
    for (int o = 1; o < 32; o <<= 1) rmax = fmaxf(rmax, __shfl_xor(rmax, o));
    float rs = (rmax > 0.f) ? 255.0f / rmax : 0.0f;
    unsigned pk = 0;
#pragma unroll
    for (int k = 0; k < 4; ++k) {
        float a = fminf(h[k] * rs, 255.0f);
        pk |= __float2uint_rn(a) << (8 * k);
    }
    *(unsigned*)(hact + (size_t)row * 128 + s * 4) = pk;
    if (s == 0) qs[row] = (rmax > 0.f) ? rmax * (1.0f / 255.0f) : 0.0f;
}

// ---------------- lin2 (MFMA) with fused final LayerNorm+ReLU ----------------
__global__ __launch_bounds__(256) void k_lin2m(const unsigned short* __restrict__ outb,
                                               const float* __restrict__ pstat,
                                               const float* __restrict__ nw,
                                               const float* __restrict__ nb,
                                               const float* __restrict__ W,
                                               const float* __restrict__ b,
                                               float* __restrict__ out) {
    __shared__ __attribute__((aligned(16))) unsigned short Bs[8192];
    __shared__ float rr[512];
    __shared__ float lskp[128], lckp[128];
    int t = threadIdx.x;
    float s1 = 0.f, s2 = 0.f;
    for (int k = t; k < NPST; k += 256) { s1 += pstat[k]; s2 += pstat[NPST + k]; }
    rr[t] = s1; rr[256 + t] = s2;
    __syncthreads();
    for (int o = 128; o > 0; o >>= 1) {
        if (t < o) { rr[t] += rr[t + o]; rr[256 + t] += rr[256 + t + o]; }
        __syncthreads();
    }
    const float M = (float)NNODES * 128.0f;
    float mean = rr[0] / M;
    float var = rr[256] / M - mean * mean;
    float inv = 1.0f / (sqrtf(fmaxf(var, 0.0f)) + 1e-5f);
    for (int idx = t; idx < 8192; idx += 256) {
        int s = idx >> 11;
        int tt = (idx >> 9) & 3;
        int lane = (idx >> 3) & 63;
        int j = idx & 7;
        int kf = s * 32 + (lane >> 4) * 8 + j;
        int k = invp(kf);
        int n = tt * 16 + (lane & 15);
        Bs[idx] = f2b(W[k * 64 + n]);
    }
    if (t < 128) {
        int d = invp(t);
        float sk = inv * nw[d];
        lskp[t] = sk;
        lckp[t] = nb[d] - mean * sk;
    }
    __syncthreads();

    int w = t >> 6, lane = t & 63;
    int q = lane >> 4, r = lane & 15;
    int m0 = blockIdx.x * 64 + w * 16;
    int mA = m0 + r; if (mA > NNODES - 1) mA = NNODES - 1;
    const unsigned short* arow = outb + (size_t)mA * 128;

    f32x4 acc[4];
#pragma unroll
    for (int tt = 0; tt < 4; ++tt) {
        float bv = b[tt * 16 + r];
        acc[tt] = (f32x4){bv, bv, bv, bv};
    }
#pragma unroll
    for (int s = 0; s < 4; ++s) {
        bhalf8 raw = *(const bhalf8*)(arow + s * 32 + q * 8);
        bhalf8 af;
#pragma unroll
        for (int j = 0; j < 8; ++j) {
            int p = s * 32 + q * 8 + j;
            float v = b2f((unsigned short)raw[j]);
            v = fmaxf(fmaf(v, lskp[p], lckp[p]), 0.0f);
            af[j] = (short)f2b(v);
        }
#pragma unroll
        for (int tt = 0; tt < 4; ++tt) {
            bhalf8 bf = *(const bhalf8*)&Bs[((s * 4 + tt) << 9) + lane * 8];
            acc[tt] = __builtin_amdgcn_mfma_f32_16x16x32_bf16(af, bf, acc[tt], 0, 0, 0);
        }
    }
#pragma unroll
    for (int i = 0; i < 4; ++i) {
        int mm = m0 + q * 4 + i;
        if (mm < NNODES) {
#pragma unroll
            for (int tt = 0; tt < 4; ++tt)
                out[(size_t)mm * 64 + tt * 16 + r] = acc[tt][i];
        }
    }
}

// ---------------- launch ----------------

extern "C" void kernel_launch(void* const* d_in, const int* in_sizes, int n_in,
                              void* d_out, int out_size, void* d_ws, size_t ws_size,
                              hipStream_t stream) {
    const float* x      = (const float*)d_in[0];
    const int*   ei     = (const int*)d_in[1];
    const float* lin1_w = (const float*)d_in[2];
    const float* lin1_b = (const float*)d_in[3];
    const float* w1     = (const float*)d_in[4];
    const float* w2     = (const float*)d_in[5];
    const float* norm_w = (const float*)d_in[6];
    const float* norm_b = (const float*)d_in[7];
    const float* lin2_w = (const float*)d_in[8];
    const float* lin2_b = (const float*)d_in[9];
    float* out = (float*)d_out;

    const int* row = ei;
    const int* col = ei + NEDGES;

    char* p = (char*)d_ws;
    auto take = [&](size_t bytes) -> char* {
        char* r = p;
        p += (bytes + 255) & ~(size_t)255;
        return r;
    };
    unsigned short* abuf = (unsigned short*)take((size_t)NNODES * 256 * 2);  // [agg|h0] bf16 packed
    unsigned short* outb = (unsigned short*)take((size_t)NNODES * 128 * 2);  // layer out bf16 packed
    unsigned char*  hact = (unsigned char*)take((size_t)NNODES * 128);       // activated u8
    float*          qs   = (float*)take((size_t)NNODES * 4);                 // per-row dequant scale
    unsigned short* Wp   = (unsigned short*)take((size_t)NLAYERS * 32768 * 2);
    float* dinv    = (float*)take((size_t)NNODES * 4);
    float* pstat   = (float*)take((size_t)2 * NPST * 4);                     // per-block stats partials
    // contiguous zero-init zone: counts | cursor | pcnt | csr (one memset)
    size_t zhead = (size_t)NNODES * 4 * 2 + 256;
    size_t zhead_al = (zhead + 255) & ~(size_t)255;
    char* zzone    = take(zhead_al + (size_t)CSRMAX * 8);
    int*   counts  = (int*)zzone;
    int*   cursor  = (int*)(zzone + (size_t)NNODES * 4);
    int*   pcnt    = (int*)(zzone + (size_t)NNODES * 4 * 2);
    int2*  csr     = (int2*)(zzone + zhead_al);
    int*   offs    = (int*)take((size_t)(NNODES + 1) * 4);
    int*   part    = (int*)take((size_t)NSCANB * 4);

    hipMemsetAsync(zzone, 0, zhead_al + (size_t)CSRMAX * 8, stream);  // pads = {row 0, w 0}

    k_count<<<(NEDGES + 255) / 256, 256, 0, stream>>>(col, counts);
    k_scan196<<<NSCANB, 256, 0, stream>>>(counts, dinv, part, pcnt, offs);
    k_scatter<<<(NEDGES + 255) / 256, 256, 0, stream>>>(row, col, offs, cursor, dinv, csr);
    k_wcp2<<<(NLAYERS * 32768 + 255) / 256, 256, 0, stream>>>(w1, w2, Wp);
    k_lin1m<<<(NNODES + 63) / 64, 256, 0, stream>>>(x, lin1_w, lin1_b, abuf);

    for (int i = 0; i < NLAYERS; ++i) {
        if (i == 0) {
            k_spmm9<0><<<(NNODES * 32 + 255) / 256, 256, 0, stream>>>(
                nullptr, nullptr, (const unsigned char*)(abuf + 128), offs, csr, dinv, abuf);
        } else {
            k_spmm9<1><<<(NNODES * 32 + 255) / 256, 256, 0, stream>>>(
                hact, qs, nullptr, offs, csr, dinv, abuf);
        }
        k_gemm10<<<NPST, 256, 0, stream>>>(abuf, Wp + (size_t)i * 32768, outb, pstat);
        if (i < NLAYERS - 1) {
            k_actq<<<(NNODES + 7) / 8, 256, 0, stream>>>(outb, pstat,
                                                         norm_w + (size_t)i * 128,
                                                         norm_b + (size_t)i * 128,
                                                         hact, qs);
        }
    }
    k_lin2m<<<(NNODES + 63) / 64, 256, 0, stream>>>(outb, pstat,
                                                    norm_w + 7 * 128, norm_b + 7 * 128,
                                                    lin2_w, lin2_b, out);
}

// Round 11
// 501.123 us; speedup vs baseline: 2.8141x; 1.0712x over previous
//
#include <hip/hip_runtime.h>
#include <hip/hip_bf16.h>
#include <math.h>

#define NNODES 50000
#define NEDGES 500000
#define NLAYERS 8
#define NSCANB 196  // ceil(NNODES/256)
#define CSRMAX (NEDGES + 7 * NNODES)  // padded-to-8 worst case
#define NPST 782    // 391 m-tiles x 2 n-halves = gemm blocks = stat slots

typedef __attribute__((ext_vector_type(8))) short bhalf8;
typedef __attribute__((ext_vector_type(4))) float f32x4;

// K-dim permutation: packed pos p <-> natural dim d = 16*(p&7) + (p>>3).
static __device__ __forceinline__ int invp(int p) { return 16 * (p & 7) + (p >> 3); }

static __device__ __forceinline__ unsigned short f2b(float v) {
    unsigned u = __builtin_bit_cast(unsigned, v);
    u += 0x7fffu + ((u >> 16) & 1u);
    return (unsigned short)(u >> 16);
}
static __device__ __forceinline__ float b2f(unsigned short w) {
    return __builtin_bit_cast(float, (unsigned)w << 16);
}
static __device__ __forceinline__ float b2f_lo(unsigned w) {
    return __builtin_bit_cast(float, w << 16);
}
static __device__ __forceinline__ float b2f_hi(unsigned w) {
    return __builtin_bit_cast(float, w & 0xffff0000u);
}
static __device__ __forceinline__ float ub(unsigned a, int k) {
    return (float)((a >> (8 * k)) & 0xffu);  // folds to v_cvt_f32_ubyteN
}

// ---------------- graph preprocessing ----------------

__global__ void k_count(const int* __restrict__ col, int* __restrict__ counts) {
    int e = blockIdx.x * 256 + threadIdx.x;
    if (e < NEDGES) atomicAdd(&counts[col[e]], 1);
}

__global__ __launch_bounds__(256) void k_dinv_bsum(const int* __restrict__ counts,
                                                   float* __restrict__ dinv,
                                                   int* __restrict__ part) {
    __shared__ int ls[256];
    int t = threadIdx.x, i = blockIdx.x * 256 + t;
    int cnt = (i < NNODES) ? counts[i] : 0;
    if (i < NNODES) dinv[i] = rsqrtf((float)(cnt + 1));
    ls[t] = (i < NNODES) ? ((cnt + 7) & ~7) : 0;
    __syncthreads();
    for (int o = 128; o > 0; o >>= 1) {
        if (t < o) ls[t] += ls[t + o];
        __syncthreads();
    }
    if (t == 0) part[blockIdx.x] = ls[0];
}

__global__ __launch_bounds__(256) void k_pscan(int* __restrict__ part) {
    __shared__ int ls[256];
    int t = threadIdx.x;
    int v = (t < NSCANB) ? part[t] : 0;
    ls[t] = v;
    __syncthreads();
    for (int o = 1; o < 256; o <<= 1) {
        int x = (t >= o) ? ls[t - o] : 0;
        __syncthreads();
        ls[t] += x;
        __syncthreads();
    }
    if (t < NSCANB) part[t] = ls[t] - v;
}

__global__ __launch_bounds__(256) void k_offs(const int* __restrict__ counts,
                                              const int* __restrict__ part,
                                              int* __restrict__ offs) {
    __shared__ int ls[256];
    int t = threadIdx.x, i = blockIdx.x * 256 + t;
    int v = (i < NNODES) ? ((counts[i] + 7) & ~7) : 0;
    ls[t] = v;
    __syncthreads();
    for (int o = 1; o < 256; o <<= 1) {
        int x = (t >= o) ? ls[t - o] : 0;
        __syncthreads();
        ls[t] += x;
        __syncthreads();
    }
    int excl = part[blockIdx.x] + ls[t] - v;
    if (i < NNODES) offs[i] = excl;
    if (i == NNODES - 1) offs[NNODES] = excl + v;
}

// csr pre-memset to 0 -> pad entries are {row 0, w 0.0f}
__global__ void k_scatter(const int* __restrict__ row, const int* __restrict__ col,
                          const int* __restrict__ offs, int* __restrict__ cursor,
                          const float* __restrict__ dinv, int2* __restrict__ csr) {
    int e = blockIdx.x * 256 + threadIdx.x;
    if (e < NEDGES) {
        int c = col[e], r = row[e];
        int pos = offs[c] + atomicAdd(&cursor[c], 1);
        float w = dinv[r] * dinv[c];
        csr[pos] = make_int2(r, __builtin_bit_cast(int, w));
    }
}

// ---------------- folded + packed layer weights (K-permuted) ----------------
__global__ void k_wcp2(const float* __restrict__ w1, const float* __restrict__ w2,
                       unsigned short* __restrict__ Wp) {
    int idx = blockIdx.x * 256 + threadIdx.x;
    if (idx >= NLAYERS * 32768) return;
    int i = idx >> 15;
    int rem = idx & 32767;
    int s = rem >> 12;
    int t = (rem >> 9) & 7;
    int lane = (rem >> 3) & 63;
    int j = rem & 7;
    int kf = s * 32 + (lane >> 4) * 8 + j;
    int n = t * 16 + (lane & 15);
    float beta = logf(1.0f / (float)(i + 1) + 1.0f);
    float v;
    if (kf < 128) {
        int k = invp(kf);
        v = beta * w1[(i * 128 + k) * 128 + n] + ((k == n) ? (1.0f - beta) : 0.0f);
    } else {
        int k2 = invp(kf - 128);
        v = 0.5f * (beta * w2[(i * 128 + k2) * 128 + n] + ((k2 == n) ? (1.0f - beta) : 0.0f));
    }
    Wp[idx] = f2b(v);
}

// ---------------- lin1 (MFMA): h0 -> abuf[:,128:256) bf16 packed ----------------
__global__ __launch_bounds__(256) void k_lin1m(const float* __restrict__ x,
                                               const float* __restrict__ W,
                                               const float* __restrict__ b,
                                               unsigned short* __restrict__ abuf) {
    __shared__ __attribute__((aligned(16))) unsigned short Bs[8192];
    int t = threadIdx.x;
    for (int idx = t; idx < 8192; idx += 256) {
        int s = idx >> 12;
        int tt = (idx >> 9) & 7;
        int lane = (idx >> 3) & 63;
        int j = idx & 7;
        int k = s * 32 + (lane >> 4) * 8 + j;
        int n = tt * 16 + (lane & 15);
        Bs[idx] = f2b(W[k * 128 + n]);
    }
    __syncthreads();

    int w = t >> 6, lane = t & 63;
    int q = lane >> 4, r = lane & 15;
    int m0 = blockIdx.x * 64 + w * 16;
    int mA = m0 + r; if (mA > NNODES - 1) mA = NNODES - 1;
    const float* xrow = x + (size_t)mA * 64;

    f32x4 acc[8];
#pragma unroll
    for (int tt = 0; tt < 8; ++tt) {
        float bv = b[tt * 16 + r];
        acc[tt] = (f32x4){bv, bv, bv, bv};
    }
#pragma unroll
    for (int s = 0; s < 2; ++s) {
        float xv[8];
        *(float4*)&xv[0] = *(const float4*)(xrow + s * 32 + q * 8);
        *(float4*)&xv[4] = *(const float4*)(xrow + s * 32 + q * 8 + 4);
        bhalf8 ah, al;
#pragma unroll
        for (int j = 0; j < 8; ++j) {
            unsigned short hb = f2b(xv[j]);
            ah[j] = (short)hb;
            al[j] = (short)f2b(xv[j] - b2f(hb));
        }
#pragma unroll
        for (int tt = 0; tt < 8; ++tt) {
            bhalf8 bf = *(const bhalf8*)&Bs[((s * 8 + tt) << 9) + lane * 8];
            acc[tt] = __builtin_amdgcn_mfma_f32_16x16x32_bf16(ah, bf, acc[tt], 0, 0, 0);
            acc[tt] = __builtin_amdgcn_mfma_f32_16x16x32_bf16(al, bf, acc[tt], 0, 0, 0);
        }
    }
#pragma unroll
    for (int i = 0; i < 4; ++i) {
        int mm = m0 + q * 4 + i;
        if (mm < NNODES) {
            bhalf8 hv;
#pragma unroll
            for (int tt = 0; tt < 8; ++tt) hv[tt] = (short)f2b(acc[tt][i]);
            *(bhalf8*)&abuf[(size_t)mm * 256 + 128 + 8 * r] = hv;
        }
    }
}

// ---------------- SpMM: padded CSR (x8), 32-bit byte-offset gathers ----------------
template <int U8>
__global__ __launch_bounds__(256) void k_spmm9(const unsigned char* __restrict__ srcu,
                                               const float* __restrict__ qs,
                                               const unsigned char* __restrict__ srcb,
                                               const int* __restrict__ offs,
                                               const int2* __restrict__ csr,
                                               const float* __restrict__ dinv,
                                               unsigned short* __restrict__ abuf) {
    int gt = blockIdx.x * 256 + threadIdx.x;
    int c = gt >> 5;          // node (2 per wave)
    unsigned s = threadIdx.x & 31;  // packed dims [4s, 4s+4)
    if (c >= NNODES) return;
    unsigned s4 = s * 4, s8 = s * 8;
    float di = dinv[c];
    float dw = di * di;
    float acc0, acc1, acc2, acc3;
    if (U8) {
        unsigned a = *(const unsigned*)(srcu + (((unsigned)c << 7) + s4));
        float dws = dw * qs[c];
        acc0 = dws * ub(a, 0); acc1 = dws * ub(a, 1);
        acc2 = dws * ub(a, 2); acc3 = dws * ub(a, 3);
    } else {
        uint2 g = *(const uint2*)(srcb + (((unsigned)c << 9) + s8));
        acc0 = dw * b2f_lo(g.x); acc1 = dw * b2f_hi(g.x);
        acc2 = dw * b2f_lo(g.y); acc3 = dw * b2f_hi(g.y);
    }
    int e = offs[c], e1 = offs[c + 1];  // multiples of 8; pads have w=0
    for (; e < e1; e += 8) {
        int2 E[8];
#pragma unroll
        for (int u = 0; u < 8; ++u) E[u] = csr[e + u];
        if (U8) {
            unsigned a[8];
            float wv[8];
#pragma unroll
            for (int u = 0; u < 8; ++u) {
                wv[u] = __builtin_bit_cast(float, E[u].y) * qs[E[u].x];
                a[u] = *(const unsigned*)(srcu + (((unsigned)E[u].x << 7) + s4));
            }
#pragma unroll
            for (int u = 0; u < 8; ++u) {
                acc0 = fmaf(wv[u], ub(a[u], 0), acc0);
                acc1 = fmaf(wv[u], ub(a[u], 1), acc1);
                acc2 = fmaf(wv[u], ub(a[u], 2), acc2);
                acc3 = fmaf(wv[u], ub(a[u], 3), acc3);
            }
        } else {
            uint2 g[8];
#pragma unroll
            for (int u = 0; u < 8; ++u)
                g[u] = *(const uint2*)(srcb + (((unsigned)E[u].x << 9) + s8));
#pragma unroll
            for (int u = 0; u < 8; ++u) {
                float wv = __builtin_bit_cast(float, E[u].y);
                acc0 = fmaf(wv, b2f_lo(g[u].x), acc0);
                acc1 = fmaf(wv, b2f_hi(g[u].x), acc1);
                acc2 = fmaf(wv, b2f_lo(g[u].y), acc2);
                acc3 = fmaf(wv, b2f_hi(g[u].y), acc3);
            }
        }
    }
    uint2 outv;
    outv.x = (unsigned)f2b(0.5f * acc0) | ((unsigned)f2b(0.5f * acc1) << 16);
    outv.y = (unsigned)f2b(0.5f * acc2) | ((unsigned)f2b(0.5f * acc3) << 16);
    *(uint2*)((unsigned char*)abuf + (((unsigned)c << 9) + s8)) = outv;
}

// ---------------- layer GEMM v10: M=128 x N=64, atomic-free stats, A prefetch ----
// grid = 391*2 = 782 blocks: mt = bx>>1, nh = bx&1. Proven 22us/layer (round 8).
__global__ __launch_bounds__(256) void k_gemm10(const unsigned short* __restrict__ A,
                                                const unsigned short* __restrict__ Bp,
                                                unsigned short* __restrict__ outb,
                                                float* __restrict__ pstat) {
    __shared__ __attribute__((aligned(16))) unsigned short Bs[16384];  // 32 KB
    __shared__ float wred[8];
    int t = threadIdx.x;
    int mt = blockIdx.x >> 1, nh = blockIdx.x & 1;
#pragma unroll
    for (int it = 0; it < 8; ++it) {
        int o = it * 2048 + t * 8;
        int g = o >> 9;
        int s = g >> 2, ntl = g & 3;
        int src = (((s * 8) + ntl + 4 * nh) << 9) + (o & 511);
        *(bhalf8*)&Bs[o] = *(const bhalf8*)&Bp[src];
    }

    int w = t >> 6, lane = t & 63;
    int q = lane >> 4, r = lane & 15;
    float ps1 = 0.f, ps2 = 0.f;

    // issue BOTH sub-tiles' A loads before the barrier (overlap B-fill + sub0 MFMA)
    int m0a = mt * 128 + w * 16;
    int m0b = m0a + 64;
    int mAa = m0a + r; if (mAa > NNODES - 1) mAa = NNODES - 1;
    int mAb = m0b + r; if (mAb > NNODES - 1) mAb = NNODES - 1;
    const unsigned short* ra = A + (size_t)mAa * 256;
    const unsigned short* rb = A + (size_t)mAb * 256;
    bhalf8 af0[8], af1[8];
#pragma unroll
    for (int s = 0; s < 8; ++s) af0[s] = *(const bhalf8*)(ra + s * 32 + q * 8);
#pragma unroll
    for (int s = 0; s < 8; ++s) af1[s] = *(const bhalf8*)(rb + s * 32 + q * 8);

    __syncthreads();  // Bs ready

    // ---- sub 0 ----
    {
        f32x4 acc[4];
#pragma unroll
        for (int i = 0; i < 4; ++i) acc[i] = (f32x4){0.f, 0.f, 0.f, 0.f};
#pragma unroll
        for (int s = 0; s < 8; ++s) {
#pragma unroll
            for (int ntl = 0; ntl < 4; ++ntl) {
                bhalf8 bfr = *(const bhalf8*)&Bs[((s * 4 + ntl) << 9) + lane * 8];
                acc[ntl] = __builtin_amdgcn_mfma_f32_16x16x32_bf16(af0[s], bfr, acc[ntl], 0, 0, 0);
            }
        }
#pragma unroll
        for (int i = 0; i < 4; ++i) {
            int mm = m0a + q * 4 + i;
            if (mm < NNODES) {
                unsigned lo = 0, hi = 0;
#pragma unroll
                for (int ntl = 0; ntl < 4; ++ntl) {
                    float v = acc[ntl][i];
                    ps1 += v; ps2 += v * v;
                    unsigned bits = (unsigned)f2b(v);
                    if (ntl < 2) lo |= bits << (16 * ntl);
                    else         hi |= bits << (16 * (ntl - 2));
                }
                *(uint2*)&outb[(size_t)mm * 128 + 8 * r + 4 * nh] = make_uint2(lo, hi);
            }
        }
    }
    // ---- sub 1 ----
    {
        f32x4 acc[4];
#pragma unroll
        for (int i = 0; i < 4; ++i) acc[i] = (f32x4){0.f, 0.f, 0.f, 0.f};
#pragma unroll
        for (int s = 0; s < 8; ++s) {
#pragma unroll
            for (int ntl = 0; ntl < 4; ++ntl) {
                bhalf8 bfr = *(const bhalf8*)&Bs[((s * 4 + ntl) << 9) + lane * 8];
                acc[ntl] = __builtin_amdgcn_mfma_f32_16x16x32_bf16(af1[s], bfr, acc[ntl], 0, 0, 0);
            }
        }
#pragma unroll
        for (int i = 0; i < 4; ++i) {
            int mm = m0b + q * 4 + i;
            if (mm < NNODES) {
                unsigned lo = 0, hi = 0;
#pragma unroll
                for (int ntl = 0; ntl < 4; ++ntl) {
                    float v = acc[ntl][i];
                    ps1 += v; ps2 += v * v;
                    unsigned bits = (unsigned)f2b(v);
                    if (ntl < 2) lo |= bits << (16 * ntl);
                    else         hi |= bits << (16 * (ntl - 2));
                }
                *(uint2*)&outb[(size_t)mm * 128 + 8 * r + 4 * nh] = make_uint2(lo, hi);
            }
        }
    }
    // ---- stats: wave shfl-reduce, one plain store per block (no atomics) ----
#pragma unroll
    for (int o = 1; o < 64; o <<= 1) {
        ps1 += __shfl_xor(ps1, o);
        ps2 += __shfl_xor(ps2, o);
    }
    if (lane == 0) { wred[w] = ps1; wred[4 + w] = ps2; }
    __syncthreads();
    if (t == 0) {
        pstat[blockIdx.x] = wred[0] + wred[1] + wred[2] + wred[3];
        pstat[NPST + blockIdx.x] = wred[4] + wred[5] + wred[6] + wred[7];
    }
}

// ---------------- activation v2: 32 rows/block (amortize pstat reduce 4x) -------
__global__ __launch_bounds__(256) void k_actq(const unsigned short* __restrict__ outb,
                                              const float* __restrict__ pstat,
                                              const float* __restrict__ nw,
                                              const float* __restrict__ nb,
                                              unsigned char* __restrict__ hact,
                                              float* __restrict__ qs) {
    __shared__ float rr[512];
    __shared__ float skp[128], ckp[128];
    int t = threadIdx.x;
    float s1 = 0.f, s2 = 0.f;
    for (int k = t; k < NPST; k += 256) { s1 += pstat[k]; s2 += pstat[NPST + k]; }
    rr[t] = s1; rr[256 + t] = s2;
    __syncthreads();
    for (int o = 128; o > 0; o >>= 1) {
        if (t < o) { rr[t] += rr[t + o]; rr[256 + t] += rr[256 + t + o]; }
        __syncthreads();
    }
    const float M = (float)NNODES * 128.0f;
    float mean = rr[0] / M;
    float var = rr[256] / M - mean * mean;
    float inv = 1.0f / (sqrtf(fmaxf(var, 0.0f)) + 1e-5f);
    if (t < 128) {
        int d = invp(t);
        float sk = inv * nw[d];
        skp[t] = sk;
        ckp[t] = nb[d] - mean * sk;
    }
    __syncthreads();
    int s = t & 31;
    int r0 = blockIdx.x * 32;
#pragma unroll 1
    for (int ii = 0; ii < 4; ++ii) {
        int row = r0 + ii * 8 + (t >> 5);
        if (row < NNODES) {
            uint2 g = *(const uint2*)(outb + (size_t)row * 128 + s * 4);
            float h[4];
            h[0] = fmaxf(fmaf(b2f_lo(g.x), skp[4 * s + 0], ckp[4 * s + 0]), 0.0f);
            h[1] = fmaxf(fmaf(b2f_hi(g.x), skp[4 * s + 1], ckp[4 * s + 1]), 0.0f);
            h[2] = fmaxf(fmaf(b2f_lo(g.y), skp[4 * s + 2], ckp[4 * s + 2]), 0.0f);
            h[3] = fmaxf(fmaf(b2f_hi(g.y), skp[4 * s + 3], ckp[4 * s + 3]), 0.0f);
            float rmax = fmaxf(fmaxf(h[0], h[1]), fmaxf(h[2], h[3]));
#pragma unroll
            for (int o = 1; o < 32; o <<= 1) rmax = fmaxf(rmax, __shfl_xor(rmax, o));
            float rs = (rmax > 0.f) ? 255.0f / rmax : 0.0f;
            unsigned pk = 0;
#pragma unroll
            for (int k = 0; k < 4; ++k) {
                float a = fminf(h[k] * rs, 255.0f);
                pk |= __float2uint_rn(a) << (8 * k);
            }
            *(unsigned*)(hact + (size_t)row * 128 + s * 4) = pk;
            if (s == 0) qs[row] = (rmax > 0.f) ? rmax * (1.0f / 255.0f) : 0.0f;
        }
    }
}

// ---------------- lin2 (MFMA) with fused final LayerNorm+ReLU ----------------
__global__ __launch_bounds__(256) void k_lin2m(const unsigned short* __restrict__ outb,
                                               const float* __restrict__ pstat,
                                               const float* __restrict__ nw,
                                               const float* __restrict__ nb,
                                               const float* __restrict__ W,
                                               const float* __restrict__ b,
                                               float* __restrict__ out) {
    __shared__ __attribute__((aligned(16))) unsigned short Bs[8192];
    __shared__ float rr[512];
    __shared__ float lskp[128], lckp[128];
    int t = threadIdx.x;
    float s1 = 0.f, s2 = 0.f;
    for (int k = t; k < NPST; k += 256) { s1 += pstat[k]; s2 += pstat[NPST + k]; }
    rr[t] = s1; rr[256 + t] = s2;
    __syncthreads();
    for (int o = 128; o > 0; o >>= 1) {
        if (t < o) { rr[t] += rr[t + o]; rr[256 + t] += rr[256 + t + o]; }
        __syncthreads();
    }
    const float M = (float)NNODES * 128.0f;
    float mean = rr[0] / M;
    float var = rr[256] / M - mean * mean;
    float inv = 1.0f / (sqrtf(fmaxf(var, 0.0f)) + 1e-5f);
    for (int idx = t; idx < 8192; idx += 256) {
        int s = idx >> 11;
        int tt = (idx >> 9) & 3;
        int lane = (idx >> 3) & 63;
        int j = idx & 7;
        int kf = s * 32 + (lane >> 4) * 8 + j;
        int k = invp(kf);
        int n = tt * 16 + (lane & 15);
        Bs[idx] = f2b(W[k * 64 + n]);
    }
    if (t < 128) {
        int d = invp(t);
        float sk = inv * nw[d];
        lskp[t] = sk;
        lckp[t] = nb[d] - mean * sk;
    }
    __syncthreads();

    int w = t >> 6, lane = t & 63;
    int q = lane >> 4, r = lane & 15;
    int m0 = blockIdx.x * 64 + w * 16;
    int mA = m0 + r; if (mA > NNODES - 1) mA = NNODES - 1;
    const unsigned short* arow = outb + (size_t)mA * 128;

    f32x4 acc[4];
#pragma unroll
    for (int tt = 0; tt < 4; ++tt) {
        float bv = b[tt * 16 + r];
        acc[tt] = (f32x4){bv, bv, bv, bv};
    }
#pragma unroll
    for (int s = 0; s < 4; ++s) {
        bhalf8 raw = *(const bhalf8*)(arow + s * 32 + q * 8);
        bhalf8 af;
#pragma unroll
        for (int j = 0; j < 8; ++j) {
            int p = s * 32 + q * 8 + j;
            float v = b2f((unsigned short)raw[j]);
            v = fmaxf(fmaf(v, lskp[p], lckp[p]), 0.0f);
            af[j] = (short)f2b(v);
        }
#pragma unroll
        for (int tt = 0; tt < 4; ++tt) {
            bhalf8 bf = *(const bhalf8*)&Bs[((s * 4 + tt) << 9) + lane * 8];
            acc[tt] = __builtin_amdgcn_mfma_f32_16x16x32_bf16(af, bf, acc[tt], 0, 0, 0);
        }
    }
#pragma unroll
    for (int i = 0; i < 4; ++i) {
        int mm = m0 + q * 4 + i;
        if (mm < NNODES) {
#pragma unroll
            for (int tt = 0; tt < 4; ++tt)
                out[(size_t)mm * 64 + tt * 16 + r] = acc[tt][i];
        }
    }
}

// ---------------- launch ----------------

extern "C" void kernel_launch(void* const* d_in, const int* in_sizes, int n_in,
                              void* d_out, int out_size, void* d_ws, size_t ws_size,
                              hipStream_t stream) {
    const float* x      = (const float*)d_in[0];
    const int*   ei     = (const int*)d_in[1];
    const float* lin1_w = (const float*)d_in[2];
    const float* lin1_b = (const float*)d_in[3];
    const float* w1     = (const float*)d_in[4];
    const float* w2     = (const float*)d_in[5];
    const float* norm_w = (const float*)d_in[6];
    const float* norm_b = (const float*)d_in[7];
    const float* lin2_w = (const float*)d_in[8];
    const float* lin2_b = (const float*)d_in[9];
    float* out = (float*)d_out;

    const int* row = ei;
    const int* col = ei + NEDGES;

    char* p = (char*)d_ws;
    auto take = [&](size_t bytes) -> char* {
        char* r = p;
        p += (bytes + 255) & ~(size_t)255;
        return r;
    };
    unsigned short* abuf = (unsigned short*)take((size_t)NNODES * 256 * 2);  // [agg|h0] bf16 packed
    unsigned short* outb = (unsigned short*)take((size_t)NNODES * 128 * 2);  // layer out bf16 packed
    unsigned char*  hact = (unsigned char*)take((size_t)NNODES * 128);       // activated u8
    float*          qs   = (float*)take((size_t)NNODES * 4);                 // per-row dequant scale
    unsigned short* Wp   = (unsigned short*)take((size_t)NLAYERS * 32768 * 2);
    float* dinv    = (float*)take((size_t)NNODES * 4);
    float* pstat   = (float*)take((size_t)2 * NPST * 4);                     // per-block stats partials
    // contiguous zero-init zone: counts | cursor | csr (one memset)
    size_t zhead = (size_t)NNODES * 4 * 2 + 256;
    size_t zhead_al = (zhead + 255) & ~(size_t)255;
    char* zzone    = take(zhead_al + (size_t)CSRMAX * 8);
    int*   counts  = (int*)zzone;
    int*   cursor  = (int*)(zzone + (size_t)NNODES * 4);
    int2*  csr     = (int2*)(zzone + zhead_al);
    int*   offs    = (int*)take((size_t)(NNODES + 1) * 4);
    int*   part    = (int*)take((size_t)NSCANB * 4);

    hipMemsetAsync(zzone, 0, zhead_al + (size_t)CSRMAX * 8, stream);  // pads = {row 0, w 0}

    k_count<<<(NEDGES + 255) / 256, 256, 0, stream>>>(col, counts);
    k_dinv_bsum<<<NSCANB, 256, 0, stream>>>(counts, dinv, part);
    k_pscan<<<1, 256, 0, stream>>>(part);
    k_offs<<<NSCANB, 256, 0, stream>>>(counts, part, offs);
    k_scatter<<<(NEDGES + 255) / 256, 256, 0, stream>>>(row, col, offs, cursor, dinv, csr);
    k_wcp2<<<(NLAYERS * 32768 + 255) / 256, 256, 0, stream>>>(w1, w2, Wp);
    k_lin1m<<<(NNODES + 63) / 64, 256, 0, stream>>>(x, lin1_w, lin1_b, abuf);

    for (int i = 0; i < NLAYERS; ++i) {
        if (i == 0) {
            k_spmm9<0><<<(NNODES * 32 + 255) / 256, 256, 0, stream>>>(
                nullptr, nullptr, (const unsigned char*)(abuf + 128), offs, csr, dinv, abuf);
        } else {
            k_spmm9<1><<<(NNODES * 32 + 255) / 256, 256, 0, stream>>>(
                hact, qs, nullptr, offs, csr, dinv, abuf);
        }
        k_gemm10<<<NPST, 256, 0, stream>>>(abuf, Wp + (size_t)i * 32768, outb, pstat);
        if (i < NLAYERS - 1) {
            k_actq<<<(NNODES + 31) / 32, 256, 0, stream>>>(outb, pstat,
                                                           norm_w + (size_t)i * 128,
                                                           norm_b + (size_t)i * 128,
                                                           hact, qs);
        }
    }
    k_lin2m<<<(NNODES + 63) / 64, 256, 0, stream>>>(outb, pstat,
                                                    norm_w + 7 * 128, norm_b + 7 * 128,
                                                    lin2_w, lin2_b, out);
}